// Round 1
// baseline (704.735 us; speedup 1.0000x reference)
//
#include <hip/hip_runtime.h>
#include <math.h>

#define B_ 8
#define V_ 25000
#define F_ 20000
#define DOUT 1056
#define FPB 32
#define GROUPS (F_ / FPB) /* 625 */
#define NTHREADS 256

typedef float f4 __attribute__((ext_vector_type(4)));

__device__ __forceinline__ f4 ld4(const float* p) { return *(const f4*)p; }

__device__ __forceinline__ float clipc(float x) {
    return fminf(fmaxf(x, -1.0f + 1e-5f), 1.0f - 1e-5f);
}

// Per-face scalar LDS layout (stride 20 floats, 16B-aligned rows):
// [0..8]  = face_coords x0..x8 (v0,v1,v2 xyz)
// [12..14]= angles, [15] = area
// [16..18]= normals, [19] = emnoangle
__global__ __launch_bounds__(NTHREADS) void mesh_encode_kernel(
    const float* __restrict__ vertices,
    const int*   __restrict__ faces,
    const float* __restrict__ theta,
    const float* __restrict__ phi,
    const float* __restrict__ freq,
    const float* __restrict__ W_angle,  const float* __restrict__ b_angle,
    const float* __restrict__ W_area,   const float* __restrict__ b_area,
    const float* __restrict__ W_normal, const float* __restrict__ b_normal,
    const float* __restrict__ W_emno,   const float* __restrict__ b_emno,
    const float* __restrict__ W_emang,  const float* __restrict__ b_emang,
    const float* __restrict__ W_emfr,   const float* __restrict__ b_emfr,
    const float* __restrict__ W_coor,   const float* __restrict__ b_coor,
    float* __restrict__ out)
{
    __shared__ __align__(16) float s_face[FPB][20];

    const int tid = threadIdx.x;
    const int b   = blockIdx.x / GROUPS;
    const int g   = blockIdx.x % GROUPS;
    const int f0  = g * FPB;

    const float DEG2RAD = 0.017453292519943295f;
    const float th = theta[b] * DEG2RAD;
    const float ph = phi[b] * DEG2RAD;
    const float sph = sinf(ph), cph = cosf(ph);
    const float sth = sinf(th), cth = cosf(th);
    const float incx = sph * cth, incy = sph * sth, incz = cph;

    // ---------------- Phase 1: geometry for FPB faces ----------------
    if (tid < FPB) {
        const int f = f0 + tid;
        const int fb = (b * F_ + f) * 3;
        const int i0 = faces[fb], i1 = faces[fb + 1], i2 = faces[fb + 2];
        const float* vb = vertices + (size_t)b * (V_ * 3);
        const float v0x = vb[3*i0], v0y = vb[3*i0+1], v0z = vb[3*i0+2];
        const float v1x = vb[3*i1], v1y = vb[3*i1+1], v1z = vb[3*i1+2];
        const float v2x = vb[3*i2], v2y = vb[3*i2+1], v2z = vb[3*i2+2];

        float* s = s_face[tid];
        s[0]=v0x; s[1]=v0y; s[2]=v0z; s[3]=v1x; s[4]=v1y; s[5]=v1z;
        s[6]=v2x; s[7]=v2y; s[8]=v2z;

        // edges = face_coords - [v2,v0,v1]
        const float e0x=v0x-v2x, e0y=v0y-v2y, e0z=v0z-v2z;
        const float e1x=v1x-v0x, e1y=v1y-v0y, e1z=v1z-v0z;
        const float e2x=v2x-v1x, e2y=v2y-v1y, e2z=v2z-v1z;

        const float d0 = fmaxf(sqrtf(e0x*e0x+e0y*e0y+e0z*e0z), 1e-12f);
        const float d1 = fmaxf(sqrtf(e1x*e1x+e1y*e1y+e1z*e1z), 1e-12f);
        const float d2 = fmaxf(sqrtf(e2x*e2x+e2y*e2y+e2z*e2z), 1e-12f);
        const float n0x=e0x/d0, n0y=e0y/d0, n0z=e0z/d0;
        const float n1x=e1x/d1, n1y=e1y/d1, n1z=e1z/d1;
        const float n2x=e2x/d2, n2y=e2y/d2, n2z=e2z/d2;

        // nd[c] = -sum_e nv[e][c]*nv[e][(c+2)%3]
        const float nd0 = -(n0x*n0z + n1x*n1z + n2x*n2z);
        const float nd1 = -(n0y*n0x + n1y*n1x + n2y*n2x);
        const float nd2 = -(n0z*n0y + n1z*n1y + n2z*n2y);
        s[12] = acosf(clipc(nd0));
        s[13] = acosf(clipc(nd1));
        s[14] = acosf(clipc(nd2));

        // cross(e0, e1)
        const float cx = e0y*e1z - e0z*e1y;
        const float cy = e0z*e1x - e0x*e1z;
        const float cz = e0x*e1y - e0y*e1x;
        const float cl = sqrtf(cx*cx+cy*cy+cz*cz);
        const float cd = fmaxf(cl, 1e-12f);
        const float nx = cx/cd, ny = cy/cd, nz = cz/cd;
        s[16]=nx; s[17]=ny; s[18]=nz;
        s[15]=0.5f*cl;

        const float il = fmaxf(sqrtf(incx*incx+incy*incy+incz*incz), 1e-12f);
        const float ixn = incx/il, iyn = incy/il, izn = incz/il;
        const float ndd = -(nx*ixn + ny*iyn + nz*izn);
        s[19] = acosf(clipc(ndd));
    }

    // ---------------- Phase 2 setup: per-thread static output slot ----------------
    const int j = tid * 4;  // float4 slot; all segment boundaries are %4==0
    f4 w0{}, w1{}, w2{}, w3{}, w4{}, w5{}, w6{}, w7{}, w8{};
    f4 bias{};
    int seg;
    if (j < 576) {                       // e_coor: x(9) @ W_coor
        seg = 0;
        w0 = ld4(W_coor + 0*576 + j);
        w1 = ld4(W_coor + 1*576 + j);
        w2 = ld4(W_coor + 2*576 + j);
        w3 = ld4(W_coor + 3*576 + j);
        w4 = ld4(W_coor + 4*576 + j);
        w5 = ld4(W_coor + 5*576 + j);
        w6 = ld4(W_coor + 6*576 + j);
        w7 = ld4(W_coor + 7*576 + j);
        w8 = ld4(W_coor + 8*576 + j);
        bias = ld4(b_coor + j);
    } else if (j < 624) {                // e_angle: angles(3) @ W_angle
        seg = 1;
        const int k = j - 576;
        w0 = ld4(W_angle + k);
        w1 = ld4(W_angle + 48 + k);
        w2 = ld4(W_angle + 96 + k);
        bias = ld4(b_angle + k);
    } else if (j < 816) {                // e_normal: normals(3) @ W_normal
        seg = 2;
        const int k = j - 624;
        w0 = ld4(W_normal + k);
        w1 = ld4(W_normal + 192 + k);
        w2 = ld4(W_normal + 384 + k);
        bias = ld4(b_normal + k);
    } else if (j < 832) {                // e_area
        seg = 3;
        const int k = j - 816;
        w0 = ld4(W_area + k);
        bias = ld4(b_area + k);
    } else {                             // e_emangle: per-batch constant
        seg = 4;
        const int k = j - 832;
        const f4 a0 = ld4(W_emang + k);
        const f4 a1 = ld4(W_emang + 192 + k);
        const f4 a2 = ld4(W_emang + 384 + k);
        const f4 bb = ld4(b_emang + k);
        bias.x = bb.x + incx*a0.x + incy*a1.x + incz*a2.x;
        bias.y = bb.y + incx*a0.y + incy*a1.y + incz*a2.y;
        bias.z = bb.z + incx*a0.z + incy*a1.z + incz*a2.z;
        bias.w = bb.w + incx*a0.w + incy*a1.w + incz*a2.w;
    }

    // Extra slot for columns 1024..1055 (threads 0..7): emnoangle / emfreq
    f4 wF{}, biasF{};
    const bool hasF  = (tid < 8);
    const bool fEmno = (tid < 4);
    if (tid < 4) {
        const int k = 4 * tid;
        wF = ld4(W_emno + k);
        biasF = ld4(b_emno + k);
    } else if (tid < 8) {
        const int k = 4 * tid - 16;
        const float flog = (log10f(freq[b]) + 1.0f) * 0.5f;  // per-batch constant
        const f4 wf = ld4(W_emfr + k);
        const f4 bf = ld4(b_emfr + k);
        biasF.x = bf.x + flog*wf.x;
        biasF.y = bf.y + flog*wf.y;
        biasF.z = bf.z + flog*wf.z;
        biasF.w = bf.w + flog*wf.w;
    }

    __syncthreads();

    // ---------------- Phase 2: stream 32 faces ----------------
    float* outg = out + ((size_t)b * F_ + f0) * DOUT;
    for (int lf = 0; lf < FPB; ++lf) {
        const float* s = s_face[lf];
        f4 v;
        if (seg == 0) {
            const f4 xa = *(const f4*)&s[0];   // x0..x3 (broadcast ds_read_b128)
            const f4 xb = *(const f4*)&s[4];   // x4..x7
            const float x8 = s[8];
            v.x = bias.x + xa.x*w0.x + xa.y*w1.x + xa.z*w2.x + xa.w*w3.x
                         + xb.x*w4.x + xb.y*w5.x + xb.z*w6.x + xb.w*w7.x + x8*w8.x;
            v.y = bias.y + xa.x*w0.y + xa.y*w1.y + xa.z*w2.y + xa.w*w3.y
                         + xb.x*w4.y + xb.y*w5.y + xb.z*w6.y + xb.w*w7.y + x8*w8.y;
            v.z = bias.z + xa.x*w0.z + xa.y*w1.z + xa.z*w2.z + xa.w*w3.z
                         + xb.x*w4.z + xb.y*w5.z + xb.z*w6.z + xb.w*w7.z + x8*w8.z;
            v.w = bias.w + xa.x*w0.w + xa.y*w1.w + xa.z*w2.w + xa.w*w3.w
                         + xb.x*w4.w + xb.y*w5.w + xb.z*w6.w + xb.w*w7.w + x8*w8.w;
        } else if (seg == 1) {
            const f4 aa = *(const f4*)&s[12];  // ang0,ang1,ang2,(area)
            v.x = bias.x + aa.x*w0.x + aa.y*w1.x + aa.z*w2.x;
            v.y = bias.y + aa.x*w0.y + aa.y*w1.y + aa.z*w2.y;
            v.z = bias.z + aa.x*w0.z + aa.y*w1.z + aa.z*w2.z;
            v.w = bias.w + aa.x*w0.w + aa.y*w1.w + aa.z*w2.w;
        } else if (seg == 2) {
            const f4 nn = *(const f4*)&s[16];  // nx,ny,nz,(emno)
            v.x = bias.x + nn.x*w0.x + nn.y*w1.x + nn.z*w2.x;
            v.y = bias.y + nn.x*w0.y + nn.y*w1.y + nn.z*w2.y;
            v.z = bias.z + nn.x*w0.z + nn.y*w1.z + nn.z*w2.z;
            v.w = bias.w + nn.x*w0.w + nn.y*w1.w + nn.z*w2.w;
        } else if (seg == 3) {
            const float ar = s[15];
            v.x = bias.x + ar*w0.x;
            v.y = bias.y + ar*w0.y;
            v.z = bias.z + ar*w0.z;
            v.w = bias.w + ar*w0.w;
        } else {
            v = bias;  // e_emangle: per-batch constant
        }
        __builtin_nontemporal_store(v, (f4*)(outg + (size_t)lf * DOUT + j));

        if (hasF) {
            f4 vF;
            if (fEmno) {
                const float em = s[19];
                vF.x = biasF.x + em*wF.x;
                vF.y = biasF.y + em*wF.y;
                vF.z = biasF.z + em*wF.z;
                vF.w = biasF.w + em*wF.w;
            } else {
                vF = biasF;  // e_emfreq: per-batch constant
            }
            __builtin_nontemporal_store(vF, (f4*)(outg + (size_t)lf * DOUT + 1024 + 4*tid));
        }
    }
}

extern "C" void kernel_launch(void* const* d_in, const int* in_sizes, int n_in,
                              void* d_out, int out_size, void* d_ws, size_t ws_size,
                              hipStream_t stream) {
    const float* vertices = (const float*)d_in[0];
    const int*   faces    = (const int*)  d_in[1];
    const float* theta    = (const float*)d_in[2];
    const float* phi      = (const float*)d_in[3];
    const float* freq     = (const float*)d_in[4];
    const float* W_angle  = (const float*)d_in[5];
    const float* b_angle  = (const float*)d_in[6];
    const float* W_area   = (const float*)d_in[7];
    const float* b_area   = (const float*)d_in[8];
    const float* W_normal = (const float*)d_in[9];
    const float* b_normal = (const float*)d_in[10];
    const float* W_emno   = (const float*)d_in[11];
    const float* b_emno   = (const float*)d_in[12];
    const float* W_emang  = (const float*)d_in[13];
    const float* b_emang  = (const float*)d_in[14];
    const float* W_emfr   = (const float*)d_in[15];
    const float* b_emfr   = (const float*)d_in[16];
    const float* W_coor   = (const float*)d_in[17];
    const float* b_coor   = (const float*)d_in[18];
    float* out = (float*)d_out;

    hipLaunchKernelGGL(mesh_encode_kernel, dim3(B_ * GROUPS), dim3(NTHREADS), 0, stream,
        vertices, faces, theta, phi, freq,
        W_angle, b_angle, W_area, b_area, W_normal, b_normal,
        W_emno, b_emno, W_emang, b_emang, W_emfr, b_emfr,
        W_coor, b_coor, out);
}